// Round 12
// baseline (490.967 us; speedup 1.0000x reference)
//
#include <hip/hip_runtime.h>
#include <hip/hip_bf16.h>

#define DM   1024
#define NE   8
#define DFF  4096
#define NTOK 4096

typedef __attribute__((ext_vector_type(8))) short bf16x8;
typedef __attribute__((ext_vector_type(4))) float f32x4;

__device__ __forceinline__ short to_bf16(float f) {
  unsigned u = __float_as_uint(f);
  unsigned r = (u + 0x7fffu + ((u >> 16) & 1u)) >> 16;   // RNE
  return (short)r;
}

__device__ __forceinline__ void gl16(const void* g, void* l) {
  __builtin_amdgcn_global_load_lds(
      (const __attribute__((address_space(1))) unsigned*)g,
      (__attribute__((address_space(3))) unsigned*)l, 16, 0, 0);
}

#define DSB do { __builtin_amdgcn_s_barrier(); __builtin_amdgcn_sched_barrier(0); } while (0)

// A&S 7.1.26 erf (abs err 1.5e-7 << bf16 rounding)
__device__ __forceinline__ float fast_gelu(float v) {
  float x  = fabsf(v) * 0.70710678118f;
  float t  = __builtin_amdgcn_rcpf(fmaf(0.3275911f, x, 1.0f));
  float p  = t * fmaf(t, fmaf(t, fmaf(t, fmaf(t, 1.061405429f, -1.453152027f),
                                      1.421413741f), -0.284496736f), 0.254829592f);
  float ex = __expf(-x * x);
  float er = fmaf(-p, ex, 1.0f);
  er = (v < 0.f) ? -er : er;
  return 0.5f * v * (1.0f + er);
}

// ---------------- router: 64 tokens/block x 4 d-quarters ----------------
__global__ __launch_bounds__(256) void router_kernel(
    const float* __restrict__ x, const float* __restrict__ gw,
    int* __restrict__ cnt, float* __restrict__ psum,
    int* __restrict__ pairs, float* __restrict__ pairW)
{
  __shared__ float gws[DM * NE];
  __shared__ float part[3][64][NE];
  const int tid = threadIdx.x;
  for (int i = tid * 4; i < DM * NE; i += 256 * 4)
    *reinterpret_cast<float4*>(&gws[i]) = *reinterpret_cast<const float4*>(&gw[i]);
  __syncthreads();

  const int tok = tid & 63;
  const int q   = tid >> 6;
  const int n   = blockIdx.x * 64 + tok;
  float acc[NE];
#pragma unroll
  for (int e = 0; e < NE; ++e) acc[e] = 0.f;

  const float4* xr = reinterpret_cast<const float4*>(x + (size_t)n * DM + q * 256);
  for (int d4 = 0; d4 < 64; ++d4) {
    float4 v = xr[d4];
    const float* gp = &gws[(q * 256 + d4 * 4) * NE];
    float xv;
#pragma unroll
    for (int dd = 0; dd < 4; ++dd) {
      xv = (dd == 0) ? v.x : (dd == 1) ? v.y : (dd == 2) ? v.z : v.w;
#pragma unroll
      for (int e = 0; e < NE; ++e) acc[e] = fmaf(xv, gp[dd * NE + e], acc[e]);
    }
  }

  if (q) {
#pragma unroll
    for (int e = 0; e < NE; ++e) part[q - 1][tok][e] = acc[e];
  }
  __syncthreads();
  if (q == 0) {
#pragma unroll
    for (int e = 0; e < NE; ++e)
      acc[e] += part[0][tok][e] + part[1][tok][e] + part[2][tok][e];

    float mx = acc[0];
#pragma unroll
    for (int e = 1; e < NE; ++e) mx = fmaxf(mx, acc[e]);
    float p[NE], s = 0.f;
#pragma unroll
    for (int e = 0; e < NE; ++e) { p[e] = expf(acc[e] - mx); s += p[e]; }
    float inv = 1.f / s;
#pragma unroll
    for (int e = 0; e < NE; ++e) {
      float v = p[e] * inv;
#pragma unroll
      for (int o = 32; o > 0; o >>= 1) v += __shfl_xor(v, o);
      if (tok == 0) atomicAdd(&psum[e], v);
    }

    float v0 = -1e30f, v1 = -1e30f; int i0 = 0, i1 = 0;
#pragma unroll
    for (int e = 0; e < NE; ++e) {
      float l = acc[e];
      if (l > v0) { v1 = v0; i1 = i0; v0 = l; i0 = e; }
      else if (l > v1) { v1 = l; i1 = e; }
    }
    float e1 = expf(v1 - v0);
    float den = 1.f + e1;
    pairW[n * 2]     = 1.f / den;
    pairW[n * 2 + 1] = e1 / den;
    int p0 = atomicAdd(&cnt[i0], 1); pairs[i0 * NTOK + p0] = n * 2;
    int p1 = atomicAdd(&cnt[i1], 1); pairs[i1 * NTOK + p1] = n * 2 + 1;
  }
}

__global__ void finalize_kernel(const int* __restrict__ cnt, int* __restrict__ off,
                                const float* __restrict__ psum, float* __restrict__ aux)
{
  if (threadIdx.x == 0 && blockIdx.x == 0) {
    int o = 0;
    for (int e = 0; e < NE; ++e) { off[e] = o; o += cnt[e]; }
    off[NE] = o;
    float a = 0.f;
    for (int e = 0; e < NE; ++e) { float me = psum[e] * (1.f / NTOK); a += me * me; }
    aux[0] = a * (float)NE;
  }
}

// ---------------- prepass: x f32 -> bf16 ----------------
__global__ __launch_bounds__(256) void convert_x_kernel(
    const float* __restrict__ x, short* __restrict__ xb)
{
  const int i = (blockIdx.x * 256 + threadIdx.x) * 8;
  float4 a = *reinterpret_cast<const float4*>(&x[i]);
  float4 b = *reinterpret_cast<const float4*>(&x[i + 4]);
  union { short s[8]; bf16x8 v; } p;
  p.s[0]=to_bf16(a.x); p.s[1]=to_bf16(a.y); p.s[2]=to_bf16(a.z); p.s[3]=to_bf16(a.w);
  p.s[4]=to_bf16(b.x); p.s[5]=to_bf16(b.y); p.s[6]=to_bf16(b.z); p.s[7]=to_bf16(b.w);
  *reinterpret_cast<bf16x8*>(&xb[i]) = p.v;
}

// ---- fast transpose: src (RxC) f32 -> dst (CxR) bf16, 128x128 tiles ----
__global__ __launch_bounds__(256) void transpose_kernel(
    const float* __restrict__ w1, const float* __restrict__ w2,
    short* __restrict__ w1t, short* __restrict__ w2t)
{
  const int z = blockIdx.z;
  const float* src; short* dst; int R, C, rt, ct;
  if (z < 8) { src = w1 + (size_t)z * DM * DFF; dst = w1t + (size_t)z * DM * DFF;
               R = DM; C = DFF; ct = blockIdx.x; rt = blockIdx.y; }
  else       { src = w2 + (size_t)(z - 8) * DM * DFF; dst = w2t + (size_t)(z - 8) * DM * DFF;
               R = DFF; C = DM; ct = blockIdx.y; rt = blockIdx.x; }
  const int r0b = rt * 128, c0b = ct * 128;

  __shared__ __attribute__((aligned(16))) short t_lds[128 * 128];

  const int tid = threadIdx.x;
  const int rq  = tid >> 4;
  const int cq  = tid & 15;

  float4 f[8][2];
  const float* sp = src + (size_t)(r0b + rq * 8) * C + c0b + cq * 8;
#pragma unroll
  for (int i = 0; i < 8; ++i) {
    f[i][0] = *reinterpret_cast<const float4*>(sp + (size_t)i * C);
    f[i][1] = *reinterpret_cast<const float4*>(sp + (size_t)i * C + 4);
  }

#pragma unroll
  for (int j = 0; j < 8; ++j) {
    float v0 = (j < 4) ? f[0][0][j] : f[0][1][j-4];
    float v1 = (j < 4) ? f[1][0][j] : f[1][1][j-4];
    float v2 = (j < 4) ? f[2][0][j] : f[2][1][j-4];
    float v3 = (j < 4) ? f[3][0][j] : f[3][1][j-4];
    float v4 = (j < 4) ? f[4][0][j] : f[4][1][j-4];
    float v5 = (j < 4) ? f[5][0][j] : f[5][1][j-4];
    float v6 = (j < 4) ? f[6][0][j] : f[6][1][j-4];
    float v7 = (j < 4) ? f[7][0][j] : f[7][1][j-4];
    int4 w;
    asm("v_cvt_pk_bf16_f32 %0, %1, %2" : "=v"(w.x) : "v"(v0), "v"(v1));
    asm("v_cvt_pk_bf16_f32 %0, %1, %2" : "=v"(w.y) : "v"(v2), "v"(v3));
    asm("v_cvt_pk_bf16_f32 %0, %1, %2" : "=v"(w.z) : "v"(v4), "v"(v5));
    asm("v_cvt_pk_bf16_f32 %0, %1, %2" : "=v"(w.w) : "v"(v6), "v"(v7));
    const int lc = cq * 8 + j;
    *reinterpret_cast<int4*>(&t_lds[lc * 128 + ((rq ^ (lc & 15)) << 3)]) = w;
  }
  __syncthreads();

#pragma unroll
  for (int v = 0; v < 2; ++v) {
    const int lc2 = (tid >> 2) + v * 64;
    short* dp = dst + (size_t)(c0b + lc2) * R + r0b;
#pragma unroll
    for (int u = 0; u < 4; ++u) {
      const int k = (tid & 3) + u * 4;
      int4 rd = *reinterpret_cast<const int4*>(&t_lds[lc2 * 128 + ((k ^ (lc2 & 15)) << 3)]);
      *reinterpret_cast<int4*>(dp + k * 8) = rd;
    }
  }
}

// ======== GEMM1: 256x128xBK32, 8 waves (4x2, wave=64x64), triple-buffer ========
// R9's proven per-wave loop; tall tile cuts LDS bytes/FLOP 1.45x.
// Stage = 2 A + 1 B gl16 per thread (3/set, 512 threads).
// vmcnt ledger: at top of iter t outstanding = sets {t,t+1} = 6 -> vmcnt(3)
// lands set t (issued 2 iters earlier). Last iter vmcnt(0). Restage target
// buf (t+2)%3 == buf of t-1 (frags consumed before barrier) -- safe as in R9.
// LDS swizzle per tile (proven): [pairs][8 chunks of 8 shorts], chunk (p,s)
// holds (row = 2p + ((s^(p&7))>>2), kchunk = (s^(p&7))&3).
__global__ __launch_bounds__(512) void gemm1_kernel(
    const short* __restrict__ xb, const short* __restrict__ w1t,
    const int* __restrict__ cnt, const int* __restrict__ off,
    const int* __restrict__ pairs, short* __restrict__ h)
{
  // bijective XCD swizzle, nwg=4096, chunk=512 = one expert per XCD
  const int wg = (blockIdx.x & 7) * 512 + (blockIdx.x >> 3);
  const int mt = wg & 15;
  const int ft = (wg >> 4) & 31;
  const int e  = wg >> 9;
  const int M  = cnt[e];
  const int m0 = mt * 256;
  if (m0 >= M) return;
  const int ff0  = ft * 128;
  const int base = off[e];

  __shared__ __attribute__((aligned(16))) short As[3][256 * 32];
  __shared__ __attribute__((aligned(16))) short Bs[3][128 * 32];

  const int tid  = threadIdx.x;
  const int lane = tid & 63;
  const int wv   = tid >> 6;     // 0..7
  const int wm   = wv >> 1;      // 0..3
  const int wn   = wv & 1;       // 0..1

  // A staging (2 slots/thread over 1024 chunks), gathered token rows
  const short* gA[2]; int lda[2];
#pragma unroll
  for (int l = 0; l < 2; ++l) {
    const int n   = l * 512 + tid;        // 0..1023
    const int p   = n >> 3;               // 0..127
    const int s   = n & 7;
    const int cip = s ^ (p & 7);
    const int row = p * 2 + (cip >> 2);   // 0..255
    const int kch = cip & 3;
    int gi = m0 + row; if (gi > M - 1) gi = M - 1;
    const int tok = pairs[e * NTOK + gi] >> 1;
    gA[l]  = xb + (size_t)tok * DM + kch * 8;
    lda[l] = n * 8;
  }
  // B staging (1 slot/thread over 512 chunks)
  const short* gB0; int ldb0;
  {
    const int n   = tid;                  // 0..511
    const int p   = n >> 3;               // 0..63
    const int s   = n & 7;
    const int cip = s ^ (p & 7);
    const int row = p * 2 + (cip >> 2);   // 0..127
    const int kch = cip & 3;
    gB0  = w1t + ((size_t)e * DFF + ff0 + row) * DM + kch * 8;
    ldb0 = n * 8;
  }

#define STAGE(buf, k0) do { \
  gl16(gA[0] + (k0), &As[buf][lda[0]]); \
  gl16(gA[1] + (k0), &As[buf][lda[1]]); \
  gl16(gB0   + (k0), &Bs[buf][ldb0]);   \
} while (0)

  const int lrw = lane & 15;
  const int sr  = ((((lane & 1) << 2) | (lane >> 4)) ^ ((lane & 15) >> 1)) * 8;
  const int ab  = (wm * 32 + (lrw >> 1)) * 64 + sr;   // + i*512, i<4
  const int bb  = (wn * 32 + (lrw >> 1)) * 64 + sr;   // + j*512, j<4

  f32x4 acc[4][4];
#pragma unroll
  for (int i = 0; i < 4; ++i)
#pragma unroll
    for (int j = 0; j < 4; ++j) acc[i][j] = (f32x4){0.f, 0.f, 0.f, 0.f};

  STAGE(0, 0);
  STAGE(1, 32);
  {
    int cur = 0, stg = 2;
    for (int t = 0; t < 32; ++t) {
      if (t < 31) { asm volatile("s_waitcnt vmcnt(3)" ::: "memory"); }
      else        { asm volatile("s_waitcnt vmcnt(0)" ::: "memory"); }
      DSB;
      if (t + 2 < 32) STAGE(stg, (t + 2) * 32);
      bf16x8 af[4], bfv[4];
#pragma unroll
      for (int i = 0; i < 4; ++i)
        af[i] = *reinterpret_cast<const bf16x8*>(&As[cur][ab + i * 512]);
#pragma unroll
      for (int j = 0; j < 4; ++j)
        bfv[j] = *reinterpret_cast<const bf16x8*>(&Bs[cur][bb + j * 512]);
#pragma unroll
      for (int i = 0; i < 4; ++i)
#pragma unroll
        for (int j = 0; j < 4; ++j)
          acc[i][j] = __builtin_amdgcn_mfma_f32_16x16x32_bf16(af[i], bfv[j], acc[i][j], 0, 0, 0);
      cur = (cur == 2) ? 0 : cur + 1;
      stg = (stg == 2) ? 0 : stg + 1;
    }
  }
#undef STAGE

  const int erow0 = m0 + wm * 64 + (lane >> 4) * 4;
  const int ecol0 = ff0 + wn * 64 + (lane & 15);
#pragma unroll
  for (int i = 0; i < 4; ++i) {
#pragma unroll
    for (int r = 0; r < 4; ++r) {
      const int grow = erow0 + i * 16 + r;
      if (grow < M) {
        short* hp = h + (size_t)(base + grow) * DFF + ecol0;
#pragma unroll
        for (int j = 0; j < 4; ++j)
          hp[j * 16] = to_bf16(fast_gelu(acc[i][j][r]));
      }
    }
  }
}

// ======== GEMM2: out += w * (h @ w2t[e]^T), K=4096 (R9 proven, unchanged) ========
__global__ __launch_bounds__(256) void gemm2_kernel(
    const short* __restrict__ h, const short* __restrict__ w2t,
    const int* __restrict__ cnt, const int* __restrict__ off,
    const int* __restrict__ pairs, const float* __restrict__ pairW,
    float* __restrict__ out)
{
  const int wg = (blockIdx.x & 7) * 256 + (blockIdx.x >> 3);
  const int dt = wg & 7;
  const int mt = (wg >> 3) & 31;
  const int e  = wg >> 8;
  const int M  = cnt[e];
  const int m0 = mt * 128;
  if (m0 >= M) return;
  const int d0   = dt * 128;
  const int base = off[e];

  __shared__ __attribute__((aligned(16))) short As[3][128 * 32];
  __shared__ __attribute__((aligned(16))) short Bs[3][128 * 32];

  const int tid  = threadIdx.x;
  const int lane = tid & 63;
  const int wv   = tid >> 6;
  const int wm   = wv >> 1;
  const int wn   = wv & 1;

  const short* gA[2]; const short* gB[2]; int ldo[2];
#pragma unroll
  for (int l = 0; l < 2; ++l) {
    const int n   = l * 256 + tid;
    const int p   = n >> 3;
    const int s   = n & 7;
    const int cip = s ^ (p & 7);
    const int row = p * 2 + (cip >> 2);
    const int kch = cip & 3;
    int gi = m0 + row; if (gi > M - 1) gi = M - 1;
    gA[l]  = h + (size_t)(base + gi) * DFF + kch * 8;
    gB[l]  = w2t + ((size_t)e * DM + d0 + row) * DFF + kch * 8;
    ldo[l] = n * 8;
  }

#define STAGE(buf, k0) do { \
  gl16(gA[0] + (k0), &As[buf][ldo[0]]); \
  gl16(gA[1] + (k0), &As[buf][ldo[1]]); \
  gl16(gB[0] + (k0), &Bs[buf][ldo[0]]); \
  gl16(gB[1] + (k0), &Bs[buf][ldo[1]]); \
} while (0)

  const int lrw = lane & 15;
  const int sr  = ((((lane & 1) << 2) | (lane >> 4)) ^ ((lane & 15) >> 1)) * 8;
  const int ab  = (wm * 32 + (lrw >> 1)) * 64 + sr;
  const int bb  = (wn * 32 + (lrw >> 1)) * 64 + sr;

  f32x4 acc[4][4];
#pragma unroll
  for (int i = 0; i < 4; ++i)
#pragma unroll
    for (int j = 0; j < 4; ++j) acc[i][j] = (f32x4){0.f, 0.f, 0.f, 0.f};
  STAGE(0, 0);
  STAGE(1, 32);
  {
    int cur = 0, stg = 2;
    for (int t = 0; t < 128; ++t) {
      if (t < 127) { asm volatile("s_waitcnt vmcnt(4)" ::: "memory"); }
      else         { asm volatile("s_waitcnt vmcnt(0)" ::: "memory"); }
      DSB;
      if (t + 2 < 128) STAGE(stg, (t + 2) * 32);
      bf16x8 af[4], bfv[4];
#pragma unroll
      for (int i = 0; i < 4; ++i)
        af[i] = *reinterpret_cast<const bf16x8*>(&As[cur][ab + i * 512]);
#pragma unroll
      for (int j = 0; j < 4; ++j)
        bfv[j] = *reinterpret_cast<const bf16x8*>(&Bs[cur][bb + j * 512]);
#pragma unroll
      for (int i = 0; i < 4; ++i)
#pragma unroll
        for (int j = 0; j < 4; ++j)
          acc[i][j] = __builtin_amdgcn_mfma_f32_16x16x32_bf16(af[i], bfv[j], acc[i][j], 0, 0, 0);
      cur = (cur == 2) ? 0 : cur + 1;
      stg = (stg == 2) ? 0 : stg + 1;
    }
  }
#undef STAGE

  const int erow0 = m0 + wm * 64 + (lane >> 4) * 4;
  const int ecol0 = d0 + wn * 64 + (lane & 15);
#pragma unroll
  for (int i = 0; i < 4; ++i) {
#pragma unroll
    for (int r = 0; r < 4; ++r) {
      const int grow = erow0 + i * 16 + r;
      if (grow < M) {
        const int pr    = pairs[e * NTOK + grow];
        const float wgt = pairW[pr];
        const int tok   = pr >> 1;
#pragma unroll
        for (int j = 0; j < 4; ++j)
          atomicAdd(&out[(size_t)tok * DM + ecol0 + j * 16], wgt * acc[i][j][r]);
      }
    }
  }
}

extern "C" void kernel_launch(void* const* d_in, const int* in_sizes, int n_in,
                              void* d_out, int out_size, void* d_ws, size_t ws_size,
                              hipStream_t stream)
{
  const float* x  = (const float*)d_in[0];
  const float* gw = (const float*)d_in[1];
  const float* w1 = (const float*)d_in[2];
  const float* w2 = (const float*)d_in[3];
  float* outf = (float*)d_out;

  int*   cnt   = (int*)d_ws;
  int*   off   = cnt + 8;
  float* psum  = (float*)(cnt + 20);
  int*   pairs = (int*)((char*)d_ws + 512);
  float* pairW = (float*)((char*)d_ws + 512 + NE * NTOK * 4);
  short* xb    = (short*)((char*)d_ws + (size_t)(1)  * (1 << 20));
  short* w1t   = (short*)((char*)d_ws + (size_t)(16) * (1 << 20));
  short* w2t   = (short*)((char*)d_ws + (size_t)(80) * (1 << 20));
  short* h     = (short*)((char*)d_ws + (size_t)(144)* (1 << 20));

  hipMemsetAsync(d_ws, 0, 512, stream);
  hipMemsetAsync(d_out, 0, (size_t)out_size * sizeof(float), stream);

  router_kernel<<<NTOK / 64, 256, 0, stream>>>(x, gw, cnt, psum, pairs, pairW);
  finalize_kernel<<<1, 64, 0, stream>>>(cnt, off, psum, outf + (size_t)NTOK * DM);
  convert_x_kernel<<<NTOK * DM / (256 * 8), 256, 0, stream>>>(x, xb);
  transpose_kernel<<<dim3(32, 8, 16), 256, 0, stream>>>(w1, w2, w1t, w2t);
  gemm1_kernel<<<4096, 512, 0, stream>>>(xb, w1t, cnt, off, pairs, h);
  gemm2_kernel<<<2048, 256, 0, stream>>>(h, w2t, cnt, off, pairs, pairW, outf);
}

// Round 13
// 385.836 us; speedup vs baseline: 1.2725x; 1.2725x over previous
//
#include <hip/hip_runtime.h>
#include <hip/hip_bf16.h>

#define DM   1024
#define NE   8
#define DFF  4096
#define NTOK 4096

typedef __attribute__((ext_vector_type(8))) short bf16x8;
typedef __attribute__((ext_vector_type(4))) float f32x4;

__device__ __forceinline__ short to_bf16(float f) {
  unsigned u = __float_as_uint(f);
  unsigned r = (u + 0x7fffu + ((u >> 16) & 1u)) >> 16;   // RNE
  return (short)r;
}

__device__ __forceinline__ void gl16(const void* g, void* l) {
  __builtin_amdgcn_global_load_lds(
      (const __attribute__((address_space(1))) unsigned*)g,
      (__attribute__((address_space(3))) unsigned*)l, 16, 0, 0);
}

#define DSB do { __builtin_amdgcn_s_barrier(); __builtin_amdgcn_sched_barrier(0); } while (0)

// A&S 7.1.26 erf (abs err 1.5e-7 << bf16 rounding)
__device__ __forceinline__ float fast_gelu(float v) {
  float x  = fabsf(v) * 0.70710678118f;
  float t  = __builtin_amdgcn_rcpf(fmaf(0.3275911f, x, 1.0f));
  float p  = t * fmaf(t, fmaf(t, fmaf(t, fmaf(t, 1.061405429f, -1.453152027f),
                                      1.421413741f), -0.284496736f), 0.254829592f);
  float ex = __expf(-x * x);
  float er = fmaf(-p, ex, 1.0f);
  er = (v < 0.f) ? -er : er;
  return 0.5f * v * (1.0f + er);
}

// ------- router: 64 tokens/block x 4 d-quarters, + fused x->bf16 convert -------
__global__ __launch_bounds__(256) void router_kernel(
    const float* __restrict__ x, const float* __restrict__ gw,
    int* __restrict__ cnt, float* __restrict__ psum,
    int* __restrict__ pairs, float* __restrict__ pairW,
    short* __restrict__ xb)
{
  __shared__ float gws[DM * NE];
  __shared__ float part[3][64][NE];
  const int tid = threadIdx.x;
  for (int i = tid * 4; i < DM * NE; i += 256 * 4)
    *reinterpret_cast<float4*>(&gws[i]) = *reinterpret_cast<const float4*>(&gw[i]);
  __syncthreads();

  const int tok = tid & 63;
  const int q   = tid >> 6;
  const int n   = blockIdx.x * 64 + tok;
  float acc[NE];
#pragma unroll
  for (int e = 0; e < NE; ++e) acc[e] = 0.f;

  const float4* xr = reinterpret_cast<const float4*>(x + (size_t)n * DM + q * 256);
  for (int d4 = 0; d4 < 64; ++d4) {
    float4 v = xr[d4];
    const float* gp = &gws[(q * 256 + d4 * 4) * NE];
    float xv;
#pragma unroll
    for (int dd = 0; dd < 4; ++dd) {
      xv = (dd == 0) ? v.x : (dd == 1) ? v.y : (dd == 2) ? v.z : v.w;
#pragma unroll
      for (int e = 0; e < NE; ++e) acc[e] = fmaf(xv, gp[dd * NE + e], acc[e]);
    }
  }

  if (q) {
#pragma unroll
    for (int e = 0; e < NE; ++e) part[q - 1][tok][e] = acc[e];
  }
  __syncthreads();
  if (q == 0) {
#pragma unroll
    for (int e = 0; e < NE; ++e)
      acc[e] += part[0][tok][e] + part[1][tok][e] + part[2][tok][e];

    float mx = acc[0];
#pragma unroll
    for (int e = 1; e < NE; ++e) mx = fmaxf(mx, acc[e]);
    float p[NE], s = 0.f;
#pragma unroll
    for (int e = 0; e < NE; ++e) { p[e] = expf(acc[e] - mx); s += p[e]; }
    float inv = 1.f / s;
#pragma unroll
    for (int e = 0; e < NE; ++e) {
      float v = p[e] * inv;
#pragma unroll
      for (int o = 32; o > 0; o >>= 1) v += __shfl_xor(v, o);
      if (tok == 0) atomicAdd(&psum[e], v);
    }

    float v0 = -1e30f, v1 = -1e30f; int i0 = 0, i1 = 0;
#pragma unroll
    for (int e = 0; e < NE; ++e) {
      float l = acc[e];
      if (l > v0) { v1 = v0; i1 = i0; v0 = l; i0 = e; }
      else if (l > v1) { v1 = l; i1 = e; }
    }
    float e1 = expf(v1 - v0);
    float den = 1.f + e1;
    pairW[n * 2]     = 1.f / den;
    pairW[n * 2 + 1] = e1 / den;
    int p0 = atomicAdd(&cnt[i0], 1); pairs[i0 * NTOK + p0] = n * 2;
    int p1 = atomicAdd(&cnt[i1], 1); pairs[i1 * NTOK + p1] = n * 2 + 1;
  }

  // fused convert of this block's 64 token rows (L2-warm), coalesced
  {
    const float* xs = x + (size_t)blockIdx.x * 64 * DM;
    short* xd = xb + (size_t)blockIdx.x * 64 * DM;
#pragma unroll 4
    for (int it = 0; it < 32; ++it) {
      const int idx = (it * 256 + tid) * 8;
      float4 a = *reinterpret_cast<const float4*>(&xs[idx]);
      float4 b = *reinterpret_cast<const float4*>(&xs[idx + 4]);
      union { short s[8]; bf16x8 v; } pk;
      pk.s[0]=to_bf16(a.x); pk.s[1]=to_bf16(a.y); pk.s[2]=to_bf16(a.z); pk.s[3]=to_bf16(a.w);
      pk.s[4]=to_bf16(b.x); pk.s[5]=to_bf16(b.y); pk.s[6]=to_bf16(b.z); pk.s[7]=to_bf16(b.w);
      *reinterpret_cast<bf16x8*>(&xd[idx]) = pk.v;
    }
  }
}

__global__ void finalize_kernel(const int* __restrict__ cnt, int* __restrict__ off,
                                const float* __restrict__ psum, float* __restrict__ aux)
{
  if (threadIdx.x == 0 && blockIdx.x == 0) {
    int o = 0;
    for (int e = 0; e < NE; ++e) { off[e] = o; o += cnt[e]; }
    off[NE] = o;
    float a = 0.f;
    for (int e = 0; e < NE; ++e) { float me = psum[e] * (1.f / NTOK); a += me * me; }
    aux[0] = a * (float)NE;
  }
}

// ---- fast transpose: src (RxC) f32 -> dst (CxR) bf16, 128x128 tiles ----
__global__ __launch_bounds__(256) void transpose_kernel(
    const float* __restrict__ w1, const float* __restrict__ w2,
    short* __restrict__ w1t, short* __restrict__ w2t)
{
  const int z = blockIdx.z;
  const float* src; short* dst; int R, C, rt, ct;
  if (z < 8) { src = w1 + (size_t)z * DM * DFF; dst = w1t + (size_t)z * DM * DFF;
               R = DM; C = DFF; ct = blockIdx.x; rt = blockIdx.y; }
  else       { src = w2 + (size_t)(z - 8) * DM * DFF; dst = w2t + (size_t)(z - 8) * DM * DFF;
               R = DFF; C = DM; ct = blockIdx.y; rt = blockIdx.x; }
  const int r0b = rt * 128, c0b = ct * 128;

  __shared__ __attribute__((aligned(16))) short t_lds[128 * 128];

  const int tid = threadIdx.x;
  const int rq  = tid >> 4;
  const int cq  = tid & 15;

  float4 f[8][2];
  const float* sp = src + (size_t)(r0b + rq * 8) * C + c0b + cq * 8;
#pragma unroll
  for (int i = 0; i < 8; ++i) {
    f[i][0] = *reinterpret_cast<const float4*>(sp + (size_t)i * C);
    f[i][1] = *reinterpret_cast<const float4*>(sp + (size_t)i * C + 4);
  }

#pragma unroll
  for (int j = 0; j < 8; ++j) {
    float v0 = (j < 4) ? f[0][0][j] : f[0][1][j-4];
    float v1 = (j < 4) ? f[1][0][j] : f[1][1][j-4];
    float v2 = (j < 4) ? f[2][0][j] : f[2][1][j-4];
    float v3 = (j < 4) ? f[3][0][j] : f[3][1][j-4];
    float v4 = (j < 4) ? f[4][0][j] : f[4][1][j-4];
    float v5 = (j < 4) ? f[5][0][j] : f[5][1][j-4];
    float v6 = (j < 4) ? f[6][0][j] : f[6][1][j-4];
    float v7 = (j < 4) ? f[7][0][j] : f[7][1][j-4];
    int4 w;
    asm("v_cvt_pk_bf16_f32 %0, %1, %2" : "=v"(w.x) : "v"(v0), "v"(v1));
    asm("v_cvt_pk_bf16_f32 %0, %1, %2" : "=v"(w.y) : "v"(v2), "v"(v3));
    asm("v_cvt_pk_bf16_f32 %0, %1, %2" : "=v"(w.z) : "v"(v4), "v"(v5));
    asm("v_cvt_pk_bf16_f32 %0, %1, %2" : "=v"(w.w) : "v"(v6), "v"(v7));
    const int lc = cq * 8 + j;
    *reinterpret_cast<int4*>(&t_lds[lc * 128 + ((rq ^ (lc & 15)) << 3)]) = w;
  }
  __syncthreads();

#pragma unroll
  for (int v = 0; v < 2; ++v) {
    const int lc2 = (tid >> 2) + v * 64;
    short* dp = dst + (size_t)(c0b + lc2) * R + r0b;
#pragma unroll
    for (int u = 0; u < 4; ++u) {
      const int k = (tid & 3) + u * 4;
      int4 rd = *reinterpret_cast<const int4*>(&t_lds[lc2 * 128 + ((k ^ (lc2 & 15)) << 3)]);
      *reinterpret_cast<int4*>(dp + k * 8) = rd;
    }
  }
}

// ======= 128x128xBK32 core: TRIPLE buffer, 1 barrier/iter, depth-2 (R9 proven) =======
// vmcnt ledger: at top of iter t outstanding = sets {t, t+1} = 8 -> vmcnt(4)
// lands set t (issued 2 iters earlier). Last iter vmcnt(0). Restage target
// buf (t+2)%3 == buf of t-1 (frags already consumed before barrier) -- safe.
// LDS swizzle (proven, 0 conflicts): tile [64 pairs][8 chunks of 8 shorts],
// chunk (p,s) holds (row = 2p + ((s^(p&7))>>2), kchunk = (s^(p&7))&3).
#define GEMM_LOOP(NT)                                                              \
  f32x4 acc[4][4];                                                                 \
  _Pragma("unroll") for (int i = 0; i < 4; ++i)                                    \
    _Pragma("unroll") for (int j = 0; j < 4; ++j) acc[i][j] = (f32x4){0.f,0.f,0.f,0.f}; \
  STAGE(0, 0);                                                                     \
  STAGE(1, 32);                                                                    \
  {                                                                                \
    int cur = 0, stg = 2;                                                          \
    for (int t = 0; t < (NT); ++t) {                                               \
      if (t < (NT) - 1) { asm volatile("s_waitcnt vmcnt(4)" ::: "memory"); }       \
      else              { asm volatile("s_waitcnt vmcnt(0)" ::: "memory"); }       \
      DSB;                                                                         \
      if (t + 2 < (NT)) STAGE(stg, (t + 2) * 32);                                  \
      bf16x8 af[4], bfv[4];                                                        \
      _Pragma("unroll") for (int i = 0; i < 4; ++i)                                \
        af[i] = *reinterpret_cast<const bf16x8*>(&As[cur][ab + i * 512]);          \
      _Pragma("unroll") for (int j = 0; j < 4; ++j)                                \
        bfv[j] = *reinterpret_cast<const bf16x8*>(&Bs[cur][bb + j * 512]);         \
      _Pragma("unroll") for (int i = 0; i < 4; ++i)                                \
        _Pragma("unroll") for (int j = 0; j < 4; ++j)                              \
          acc[i][j] = __builtin_amdgcn_mfma_f32_16x16x32_bf16(af[i], bfv[j], acc[i][j], 0, 0, 0); \
      cur = (cur == 2) ? 0 : cur + 1;                                              \
      stg = (stg == 2) ? 0 : stg + 1;                                              \
    }                                                                              \
  }

// ======== GEMM1: h = gelu(gather(xb) @ w1t[e]^T) ========
__global__ __launch_bounds__(256) void gemm1_kernel(
    const short* __restrict__ xb, const short* __restrict__ w1t,
    const int* __restrict__ cnt, const int* __restrict__ off,
    const int* __restrict__ pairs, short* __restrict__ h)
{
  // bijective XCD swizzle, nwg=8192, chunk=1024 = one expert per XCD
  const int wg = (blockIdx.x & 7) * 1024 + (blockIdx.x >> 3);
  const int mt = wg & 31;
  const int ft = (wg >> 5) & 31;
  const int e  = wg >> 10;
  const int M  = cnt[e];
  const int m0 = mt * 128;
  if (m0 >= M) return;
  const int ff0  = ft * 128;
  const int base = off[e];

  __shared__ __attribute__((aligned(16))) short As[3][128 * 32];
  __shared__ __attribute__((aligned(16))) short Bs[3][128 * 32];

  const int tid  = threadIdx.x;
  const int lane = tid & 63;
  const int wv   = tid >> 6;
  const int wm   = wv >> 1;
  const int wn   = wv & 1;

  const short* gA[2]; const short* gB[2]; int ldo[2];
#pragma unroll
  for (int l = 0; l < 2; ++l) {
    const int n   = l * 256 + tid;
    const int p   = n >> 3;
    const int s   = n & 7;
    const int cip = s ^ (p & 7);
    const int row = p * 2 + (cip >> 2);
    const int kch = cip & 3;
    int gi = m0 + row; if (gi > M - 1) gi = M - 1;
    const int tok = pairs[e * NTOK + gi] >> 1;
    gA[l]  = xb + (size_t)tok * DM + kch * 8;
    gB[l]  = w1t + ((size_t)e * DFF + ff0 + row) * DM + kch * 8;
    ldo[l] = n * 8;
  }

#define STAGE(buf, k0) do { \
  gl16(gA[0] + (k0), &As[buf][ldo[0]]); \
  gl16(gA[1] + (k0), &As[buf][ldo[1]]); \
  gl16(gB[0] + (k0), &Bs[buf][ldo[0]]); \
  gl16(gB[1] + (k0), &Bs[buf][ldo[1]]); \
} while (0)

  const int lrw = lane & 15;
  const int sr  = ((((lane & 1) << 2) | (lane >> 4)) ^ ((lane & 15) >> 1)) * 8;
  const int ab  = (wm * 32 + (lrw >> 1)) * 64 + sr;
  const int bb  = (wn * 32 + (lrw >> 1)) * 64 + sr;

  GEMM_LOOP(32)
#undef STAGE

  const int erow0 = m0 + wm * 64 + (lane >> 4) * 4;
  const int ecol0 = ff0 + wn * 64 + (lane & 15);
#pragma unroll
  for (int i = 0; i < 4; ++i) {
#pragma unroll
    for (int r = 0; r < 4; ++r) {
      const int grow = erow0 + i * 16 + r;
      if (grow < M) {
        short* hp = h + (size_t)(base + grow) * DFF + ecol0;
#pragma unroll
        for (int j = 0; j < 4; ++j)
          hp[j * 16] = to_bf16(fast_gelu(acc[i][j][r]));
      }
    }
  }
}

// ======== GEMM2: out += w * (h @ w2t[e]^T), K=4096 ========
__global__ __launch_bounds__(256) void gemm2_kernel(
    const short* __restrict__ h, const short* __restrict__ w2t,
    const int* __restrict__ cnt, const int* __restrict__ off,
    const int* __restrict__ pairs, const float* __restrict__ pairW,
    float* __restrict__ out)
{
  // nwg=2048, chunk=256 = one expert per XCD; dt inner -> h panel L2 reuse
  const int wg = (blockIdx.x & 7) * 256 + (blockIdx.x >> 3);
  const int dt = wg & 7;
  const int mt = (wg >> 3) & 31;
  const int e  = wg >> 8;
  const int M  = cnt[e];
  const int m0 = mt * 128;
  if (m0 >= M) return;
  const int d0   = dt * 128;
  const int base = off[e];

  __shared__ __attribute__((aligned(16))) short As[3][128 * 32];
  __shared__ __attribute__((aligned(16))) short Bs[3][128 * 32];

  const int tid  = threadIdx.x;
  const int lane = tid & 63;
  const int wv   = tid >> 6;
  const int wm   = wv >> 1;
  const int wn   = wv & 1;

  const short* gA[2]; const short* gB[2]; int ldo[2];
#pragma unroll
  for (int l = 0; l < 2; ++l) {
    const int n   = l * 256 + tid;
    const int p   = n >> 3;
    const int s   = n & 7;
    const int cip = s ^ (p & 7);
    const int row = p * 2 + (cip >> 2);
    const int kch = cip & 3;
    int gi = m0 + row; if (gi > M - 1) gi = M - 1;
    gA[l]  = h + (size_t)(base + gi) * DFF + kch * 8;
    gB[l]  = w2t + ((size_t)e * DM + d0 + row) * DFF + kch * 8;
    ldo[l] = n * 8;
  }

#define STAGE(buf, k0) do { \
  gl16(gA[0] + (k0), &As[buf][ldo[0]]); \
  gl16(gA[1] + (k0), &As[buf][ldo[1]]); \
  gl16(gB[0] + (k0), &Bs[buf][ldo[0]]); \
  gl16(gB[1] + (k0), &Bs[buf][ldo[1]]); \
} while (0)

  const int lrw = lane & 15;
  const int sr  = ((((lane & 1) << 2) | (lane >> 4)) ^ ((lane & 15) >> 1)) * 8;
  const int ab  = (wm * 32 + (lrw >> 1)) * 64 + sr;
  const int bb  = (wn * 32 + (lrw >> 1)) * 64 + sr;

  GEMM_LOOP(128)
#undef STAGE

  const int erow0 = m0 + wm * 64 + (lane >> 4) * 4;
  const int ecol0 = d0 + wn * 64 + (lane & 15);
#pragma unroll
  for (int i = 0; i < 4; ++i) {
#pragma unroll
    for (int r = 0; r < 4; ++r) {
      const int grow = erow0 + i * 16 + r;
      if (grow < M) {
        const int pr    = pairs[e * NTOK + grow];
        const float wgt = pairW[pr];
        const int tok   = pr >> 1;
#pragma unroll
        for (int j = 0; j < 4; ++j)
          atomicAdd(&out[(size_t)tok * DM + ecol0 + j * 16], wgt * acc[i][j][r]);
      }
    }
  }
}

extern "C" void kernel_launch(void* const* d_in, const int* in_sizes, int n_in,
                              void* d_out, int out_size, void* d_ws, size_t ws_size,
                              hipStream_t stream)
{
  const float* x  = (const float*)d_in[0];
  const float* gw = (const float*)d_in[1];
  const float* w1 = (const float*)d_in[2];
  const float* w2 = (const float*)d_in[3];
  float* outf = (float*)d_out;

  int*   cnt   = (int*)d_ws;
  int*   off   = cnt + 8;
  float* psum  = (float*)(cnt + 20);
  int*   pairs = (int*)((char*)d_ws + 512);
  float* pairW = (float*)((char*)d_ws + 512 + NE * NTOK * 4);
  short* xb    = (short*)((char*)d_ws + (size_t)(1)  * (1 << 20));
  short* w1t   = (short*)((char*)d_ws + (size_t)(16) * (1 << 20));
  short* w2t   = (short*)((char*)d_ws + (size_t)(80) * (1 << 20));
  short* h     = (short*)((char*)d_ws + (size_t)(144)* (1 << 20));

  hipMemsetAsync(d_ws, 0, 512, stream);
  hipMemsetAsync(d_out, 0, (size_t)out_size * sizeof(float), stream);

  router_kernel<<<NTOK / 64, 256, 0, stream>>>(x, gw, cnt, psum, pairs, pairW, xb);
  finalize_kernel<<<1, 64, 0, stream>>>(cnt, off, psum, outf + (size_t)NTOK * DM);
  transpose_kernel<<<dim3(32, 8, 16), 256, 0, stream>>>(w1, w2, w1t, w2t);
  gemm1_kernel<<<8192, 256, 0, stream>>>(xb, w1t, cnt, off, pairs, h);
  gemm2_kernel<<<2048, 256, 0, stream>>>(h, w2t, cnt, off, pairs, pairW, outf);
}